// Round 8
// baseline (573.997 us; speedup 1.0000x reference)
//
#include <hip/hip_runtime.h>

typedef int   v4i   __attribute__((ext_vector_type(4)));
typedef unsigned long u64x2 __attribute__((ext_vector_type(2)));

#define HDIM 768
#define NTOK 32768

// ---- workspace layout (bytes) ----
static constexpr size_t WX_OFF   = 0;                   // int8 A8 [NTOK*HDIM]
static constexpr size_t WINT_OFF = 25165824;            // int8 W8 [HDIM*HDIM]
static constexpr size_t RS1_OFF  = WINT_OFF + 1179648;  // double[768]
static constexpr size_t RS2_OFF  = RS1_OFF + 6144;      // double[768]
static constexpr size_t BS_OFF   = RS2_OFF + 6144;      // float [768] bias_scale
static constexpr size_t BINT_OFF = BS_OFF + 3072;       // int   [768] b_int
static constexpr size_t LNBI_OFF = BINT_OFF + 3072;     // int   [768] LN bias_int
static constexpr size_t SFO_OFF  = LNBI_OFF + 3072;     // float [768] sf_out
static constexpr size_t SC_OFF   = SFO_OFF + 3072;      // [0]min1 [1]max1 [4]shift [5]s [6]s2 [8]srmin [9]flag
static constexpr size_t RSM1_OFF = SC_OFF + 64;         // double rs_m1
static constexpr size_t CMIN_OFF = SC_OFF + 128;        // uint[16] per-candidate encoded min
static constexpr size_t CMAX_OFF = SC_OFF + 192;        // uint[16] per-candidate encoded max
static constexpr size_t FCT_OFF  = SC_OFF + 256;        // uint[NTOK*16] per-row per-candidate factor (2 MB)

// sortable-uint encoding of float for atomic min/max
__device__ __forceinline__ unsigned fenc(float f) {
    unsigned u = __float_as_uint(f);
    return (u >> 31) ? ~u : (u | 0x80000000u);
}
__device__ __forceinline__ float fdec(unsigned e) {
    unsigned u = (e >> 31) ? (e & 0x7fffffffu) : ~e;
    return __uint_as_float(u);
}

// async global->LDS, 16B per lane; LDS base wave-uniform (HW adds lane*16)
#define GLDS16(g, l) __builtin_amdgcn_global_load_lds( \
    (const __attribute__((address_space(1))) unsigned int*)(g), \
    (__attribute__((address_space(3))) unsigned int*)(l), 16, 0, 0)

// 16B-chunk XOR swizzle within a 64B row: 2-way-only bank aliasing (free).
__device__ __forceinline__ int swz4(int r) { return (r & 3) ^ ((r >> 2) & 3); }

// ============ K0: weight quantization + per-channel tables + scalar init ============
__global__ __launch_bounds__(256) void k0_prep(const float* __restrict__ W,
                                               const float* __restrict__ bias,
                                               const float* __restrict__ ln_w,
                                               const float* __restrict__ ln_b,
                                               const float* __restrict__ phsf,
                                               char* __restrict__ ws) {
    int o = blockIdx.x, tid = threadIdx.x;
    __shared__ float red[256];
    __shared__ float fc_sh;
    float m = 0.f;
    for (int j = tid; j < HDIM; j += 256) m = fmaxf(m, fabsf(W[(size_t)o * HDIM + j]));
    red[tid] = m;
    __syncthreads();
    for (int s = 128; s; s >>= 1) { if (tid < s) red[tid] = fmaxf(red[tid], red[tid + s]); __syncthreads(); }
    if (tid == 0) {
        float fc = fmaxf(red[0], 1e-8f) / 127.0f;     // _sym_scale(8,...)
        float hsf = *phsf;
        float bs = fc * hsf;
        fc_sh = fc;
        ((float*)(ws + BS_OFF))[o] = bs;
        ((int*)(ws + BINT_OFF))[o] = (int)rintf(bias[o] / bs);   // _sym_quant(bias,32)
        float sf = sqrtf(768.0f) / 1073741824.0f;                // sqrt(H)/2^30
        float lw = ln_w[o], lb = ln_b[o];
        ((int*)(ws + LNBI_OFF))[o] = (int)floorf((lb / lw) / sf);
        ((float*)(ws + SFO_OFF))[o] = sf * lw;
    }
    __syncthreads();
    float fc = fc_sh;
    char* w8 = (char*)(ws + WINT_OFF);
    for (int j = tid; j < HDIM; j += 256) {
        float q = rintf(W[(size_t)o * HDIM + j] / fc);
        q = fminf(fmaxf(q, -127.f), 126.f);           // clip [-n, n-1]
        w8[(size_t)o * HDIM + j] = (char)q;
    }
    if (blockIdx.x == 0) {
        if (tid < 16) {
            unsigned* sc = (unsigned*)(ws + SC_OFF);
            unsigned v = 0u;
            if (tid == 0 || tid == 2) v = 0xFFFFFFFFu;    // min slots
            if (tid == 8) v = 127u;                       // srmin init
            sc[tid] = v;                                   // shift/flag/etc -> 0
        }
        if (tid >= 32 && tid < 48) {
            ((unsigned*)(ws + CMIN_OFF))[tid - 32] = 0xFFFFFFFFu;
            ((unsigned*)(ws + CMAX_OFF))[tid - 32] = 0u;
        }
    }
}

// ============ KP: hs -> int8, fully coalesced ============
__global__ __launch_bounds__(256) void kp_a8(const float* __restrict__ hs,
                                             const float* __restrict__ phsf,
                                             char* __restrict__ ws) {
    int tid = threadIdx.x;
    size_t b4 = (size_t)blockIdx.x * 1024 + tid;   // float4 slot
    float inv = 1.0f / *phsf;
    const float4* in4 = (const float4*)hs;
    unsigned* o32 = (unsigned*)(ws + WX_OFF);
    #pragma unroll
    for (int j = 0; j < 4; ++j) {
        float4 v = in4[b4 + j * 256];
        int q0 = (int)rintf(v.x * inv), q1 = (int)rintf(v.y * inv);
        int q2 = (int)rintf(v.z * inv), q3 = (int)rintf(v.w * inv);
        o32[b4 + j * 256] = (unsigned)(q0 & 255) | ((unsigned)(q1 & 255) << 8) |
                            ((unsigned)(q2 & 255) << 16) | ((unsigned)(q3 & 255) << 24);
    }
}

// ============ K1: int8 MFMA GEMM, BM=BN=128 BK=64, counted-vmcnt pipeline ============
#define BM 128
#define BN 128
#define BK 64
#define NKT (HDIM / BK)   // 12
#define SROW 132          // padded LDS row stride (ints) for the epilogue bounce
__global__ __launch_bounds__(256, 3) void k1_gemm(const float* __restrict__ inp,
                                                  char* __restrict__ ws,
                                                  int* __restrict__ accOut) {
    __shared__ alignas(16) char smem[32800];
    char* As0 = smem;                  // 2 x 8192
    char* Bs0 = smem + 16384;          // 2 x 8192
    float* rmn = (float*)(smem + 32768);
    float* rmx = rmn + 4;
    int tid = threadIdx.x, lane = tid & 63, wave = tid >> 6;
    int wrow = lane & 15, g = lane >> 4;
    int bid = blockIdx.x;
    int xcd = bid & 7, slot = bid >> 3;           // 1536 blocks: 8 XCDs x 192 slots
    int mtile = xcd * 32 + slot / 6;
    int ntile = slot % 6;
    int t0 = mtile * BM, o0 = ntile * BN;
    const char* a8 = (const char*)(ws + WX_OFF);
    const char* w8 = (const char*)(ws + WINT_OFF);

    const char* asrc[2]; const char* bsrc[2];
    int ldso[2];
    #pragma unroll
    for (int i = 0; i < 2; ++i) {
        int c = i * 256 + tid, r = c >> 2, s = c & 3;
        asrc[i] = a8 + (size_t)(t0 + r) * HDIM + (s ^ swz4(r)) * 16;
        bsrc[i] = w8 + (size_t)(o0 + r) * HDIM + (s ^ swz4(r)) * 16;
        ldso[i] = (i * 256 + wave * 64) * 16;
    }

    int wm = wave & 1, wn = wave >> 1;            // wave tile: 64(t) x 64(o)
    int aofs[4], bofs[4];
    #pragma unroll
    for (int mi = 0; mi < 4; ++mi) { int r = wm * 64 + mi * 16 + wrow; aofs[mi] = r * BK + ((g ^ swz4(r)) * 16); }
    #pragma unroll
    for (int nf = 0; nf < 4; ++nf) { int r = wn * 64 + nf * 16 + wrow; bofs[nf] = r * BK + ((g ^ swz4(r)) * 16); }

    #pragma unroll
    for (int i = 0; i < 2; ++i) GLDS16(asrc[i], As0 + ldso[i]);
    #pragma unroll
    for (int i = 0; i < 2; ++i) GLDS16(bsrc[i], Bs0 + ldso[i]);
    #pragma unroll
    for (int i = 0; i < 2; ++i) GLDS16(asrc[i] + BK, As0 + 8192 + ldso[i]);
    #pragma unroll
    for (int i = 0; i < 2; ++i) GLDS16(bsrc[i] + BK, Bs0 + 8192 + ldso[i]);
    asm volatile("s_waitcnt vmcnt(4)" ::: "memory");
    __builtin_amdgcn_s_barrier();

    v4i acc[4][4] = {};
    for (int kt = 0; kt < NKT; ++kt) {
        int cur = kt & 1;
        const char* Ac = As0 + cur * 8192;
        const char* Bc = Bs0 + cur * 8192;
        u64x2 af[4], bf[4];
        #pragma unroll
        for (int mi = 0; mi < 4; ++mi) af[mi] = *(const u64x2*)(Ac + aofs[mi]);
        #pragma unroll
        for (int nf = 0; nf < 4; ++nf) bf[nf] = *(const u64x2*)(Bc + bofs[nf]);
        asm volatile("s_waitcnt lgkmcnt(0)" ::: "memory");
        __builtin_amdgcn_s_barrier();
        if (kt + 2 < NKT) {
            #pragma unroll
            for (int i = 0; i < 2; ++i) GLDS16(asrc[i] + (kt + 2) * BK, As0 + cur * 8192 + ldso[i]);
            #pragma unroll
            for (int i = 0; i < 2; ++i) GLDS16(bsrc[i] + (kt + 2) * BK, Bs0 + cur * 8192 + ldso[i]);
        }
        __builtin_amdgcn_s_setprio(1);
        #pragma unroll
        for (int mi = 0; mi < 4; ++mi)
            #pragma unroll
            for (int nf = 0; nf < 4; ++nf) {
                acc[mi][nf] = __builtin_amdgcn_mfma_i32_16x16x32_i8((long)af[mi][0], (long)bf[nf][0], acc[mi][nf], 0, 0, 0);
                acc[mi][nf] = __builtin_amdgcn_mfma_i32_16x16x32_i8((long)af[mi][1], (long)bf[nf][1], acc[mi][nf], 0, 0, 0);
            }
        __builtin_amdgcn_s_setprio(0);
        if (kt + 2 < NKT) {
            asm volatile("s_waitcnt vmcnt(4)" ::: "memory");
            __builtin_amdgcn_s_barrier();
        } else if (kt + 2 == NKT) {
            asm volatile("s_waitcnt vmcnt(0)" ::: "memory");
            __builtin_amdgcn_s_barrier();
        }
    }

    // ---- epilogue: LDS-bounce per mi-slice, vectorized 16B global I/O ----
    const float* bscale = (const float*)(ws + BS_OFF);
    const int* bint = (const int*)(ws + BINT_OFF);
    int* sAcc = (int*)smem;
    float lmn = 3.402823466e38f, lmx = -3.402823466e38f;
    #pragma unroll
    for (int mi = 0; mi < 4; ++mi) {
        __syncthreads();
        #pragma unroll
        for (int nf = 0; nf < 4; ++nf)
            #pragma unroll
            for (int r = 0; r < 4; ++r)
                sAcc[(wm * 16 + g * 4 + r) * SROW + wn * 64 + nf * 16 + wrow] = acc[mi][nf][r];
        __syncthreads();
        #pragma unroll
        for (int k = 0; k < 4; ++k) {
            int i4 = tid + k * 256;                // 1024 int4 = 32 rows x 32 int4
            int sr = i4 >> 5, c4 = i4 & 31;
            int t = t0 + (sr >> 4) * 64 + mi * 16 + (sr & 15);
            int col = o0 + c4 * 4;
            int4 a4 = *(const int4*)&sAcc[sr * SROW + c4 * 4];
            int4 b4 = *(const int4*)&bint[col];
            float4 bs4 = *(const float4*)&bscale[col];
            a4.x += b4.x; a4.y += b4.y; a4.z += b4.z; a4.w += b4.w;
            size_t idx = (size_t)t * HDIM + col;
            *(int4*)&accOut[idx] = a4;
            float4 x4 = *(const float4*)&inp[idx];
            float xa;
            xa = (float)a4.x * bs4.x + x4.x; lmn = fminf(lmn, xa); lmx = fmaxf(lmx, xa);
            xa = (float)a4.y * bs4.y + x4.y; lmn = fminf(lmn, xa); lmx = fmaxf(lmx, xa);
            xa = (float)a4.z * bs4.z + x4.z; lmn = fminf(lmn, xa); lmx = fmaxf(lmx, xa);
            xa = (float)a4.w * bs4.w + x4.w; lmn = fminf(lmn, xa); lmx = fmaxf(lmx, xa);
        }
    }
    #pragma unroll
    for (int off = 32; off; off >>= 1) {
        lmn = fminf(lmn, __shfl_down(lmn, off));
        lmx = fmaxf(lmx, __shfl_down(lmx, off));
    }
    __syncthreads();
    if (lane == 0) { rmn[wave] = lmn; rmx[wave] = lmx; }
    __syncthreads();
    if (tid == 0) {
        float mn = fminf(fminf(rmn[0], rmn[1]), fminf(rmn[2], rmn[3]));
        float mx = fmaxf(fmaxf(rmx[0], rmx[1]), fmaxf(rmx[2], rmx[3]));
        volatile unsigned* sc = (volatile unsigned*)(ws + SC_OFF);
        unsigned emn = fenc(mn), emx = fenc(mx);
        if (emn < sc[0]) atomicMin((unsigned*)&sc[0], emn);
        if (emx > sc[1]) atomicMax((unsigned*)&sc[1], emx);
    }
}

// ============ K2: finalize ln_in_scale s + frexp tables ============
__global__ __launch_bounds__(256) void k2_scale1(const float* __restrict__ pisf, char* __restrict__ ws) {
    __shared__ float s_sh;
    unsigned* sc = (unsigned*)(ws + SC_OFF);
    if (threadIdx.x == 0) {
        float mn = fdec(sc[0]), mx = fdec(sc[1]);
        float s = fmaxf(fmaxf(fabsf(mn), fabsf(mx)), 1e-8f) / 2097151.0f;  // n = 2^21-1
        ((float*)sc)[5] = s;
        s_sh = s;
        double r = (double)(*pisf) / (double)s;
        int ex; double mant = frexp(r, &ex);
        double m1 = floor(mant * 2147483648.0 + 0.5);
        ((double*)(ws + RSM1_OFF))[0] = m1 * exp2((double)(ex - 31));
    }
    __syncthreads();
    float s = s_sh;
    const float* bs = (const float*)(ws + BS_OFF);
    double* rs1 = (double*)(ws + RS1_OFF);
    for (int o = threadIdx.x; o < HDIM; o += 256) {
        double r = (double)bs[o] / (double)s;
        int ex; double mant = frexp(r, &ex);
        double m = floor(mant * 2147483648.0 + 0.5);
        rs1[o] = m * exp2((double)(ex - 31));
    }
}

// ============ K3F: fused requant + LN stats, 4-candidate window [sr, sr+3] ============
// Global shift = max(sr) over rows. A row only needs candidates it could be
// asked for; window of 4 covers spread(sr) <= 3 (near-certain for iid token
// rows). srmin tracked globally; k5a sets a flag and k4_fb runs the exact
// single-candidate pass iff the window was insufficient.
__global__ __launch_bounds__(256) void k3f(char* __restrict__ ws, int* __restrict__ buf,
                                           const float* __restrict__ inp,
                                           const float* __restrict__ pisf) {
    int tid = threadIdx.x, lane = tid & 63, wave = tid >> 6;
    int wid = blockIdx.x * 4 + wave;
    const double* rs1 = (const double*)(ws + RS1_OFF);
    double rsm1 = *(const double*)(ws + RSM1_OFF);
    float inv_isf = 1.0f / *pisf;
    const int* lnbi = (const int*)(ws + LNBI_OFF);
    const float* sfo = (const float*)(ws + SFO_OFF);
    unsigned* fct = (unsigned*)(ws + FCT_OFF);
    volatile unsigned* cmi = (volatile unsigned*)(ws + CMIN_OFF);
    volatile unsigned* cma = (volatile unsigned*)(ws + CMAX_OFF);
    double t_rs1[12]; int t_lnbi[12]; float t_sfo[12];
    #pragma unroll
    for (int c = 0; c < 3; ++c) {
        int o0 = (lane + 64 * c) * 4;
        #pragma unroll
        for (int j = 0; j < 4; ++j) {
            t_rs1[c * 4 + j] = rs1[o0 + j];
            t_lnbi[c * 4 + j] = lnbi[o0 + j];
            t_sfo[c * 4 + j] = sfo[o0 + j];
        }
    }
    int locMax = 0, locMin = 127;
    int4 aP[3]; float4 xP[3];
    {
        size_t b0 = (size_t)(wid * 4) * HDIM;
        #pragma unroll
        for (int c = 0; c < 3; ++c) {
            aP[c] = ((const int4*)(buf + b0))[lane + 64 * c];
            xP[c] = ((const float4*)(inp + b0))[lane + 64 * c];
        }
    }
    for (int rr = 0; rr < 4; ++rr) {
        int4 aN[3]; float4 xN[3];
        if (rr < 3) {
            size_t nb = (size_t)(wid * 4 + rr + 1) * HDIM;
            #pragma unroll
            for (int c = 0; c < 3; ++c) {
                aN[c] = ((const int4*)(buf + nb))[lane + 64 * c];
                xN[c] = ((const float4*)(inp + nb))[lane + 64 * c];
            }
        }
        size_t base = (size_t)(wid * 4 + rr) * HDIM;
        int q[12];
        int sum = 0;
        #pragma unroll
        for (int c = 0; c < 3; ++c) {
            int av[4] = {aP[c].x, aP[c].y, aP[c].z, aP[c].w};
            float xv[4] = {xP[c].x, xP[c].y, xP[c].z, xP[c].w};
            #pragma unroll
            for (int j = 0; j < 4; ++j) {
                double q1 = rint((double)av[j] * t_rs1[c * 4 + j]);
                int wxj = (int)rintf(xv[j] * inv_isf);
                double qq = q1 + rint((double)wxj * rsm1);
                qq = fmin(fmax(qq, -2097152.0), 2097151.0);   // clip [-2^21, 2^21-1]
                q[c * 4 + j] = (int)qq;
                sum += q[c * 4 + j];
            }
        }
        #pragma unroll
        for (int off = 32; off; off >>= 1) sum += __shfl_xor(sum, off);
        int mean = (int)rint((double)sum / 768.0);
        long long v0 = 0;
        #pragma unroll
        for (int k = 0; k < 12; ++k) { q[k] -= mean; v0 += (long long)q[k] * (long long)q[k]; }
        #pragma unroll
        for (int off = 32; off; off >>= 1) v0 += __shfl_xor(v0, off);
        #pragma unroll
        for (int c = 0; c < 3; ++c) {
            int4 y = {q[c * 4 + 0], q[c * 4 + 1], q[c * 4 + 2], q[c * 4 + 3]};
            ((int4*)(buf + base))[lane + 64 * c] = y;
        }
        double vd = (double)(v0 < 1 ? 1LL : v0);
        int sr = (int)ceil(0.5 * log2(vd) - 16.0);        // per-row shift, provably <= 11
        if (sr < 0) sr = 0;
        if (sr > 11) sr = 11;
        locMax = max(locMax, sr);
        locMin = min(locMin, sr);
        int z[12];
        #pragma unroll
        for (int k = 0; k < 12; ++k) z[k] = q[k] >> sr;
        #pragma unroll
        for (int d = 0; d < 4; ++d) {                     // candidates s = sr+d (static d: reg-indexable)
            int s = sr + d;
            if (s < 12) {                                 // wave-uniform predicate
                long long vs;
                if (d == 0 && sr == 0) vs = v0;
                else {
                    vs = 0;
                    #pragma unroll
                    for (int k = 0; k < 12; ++k) vs += (long long)z[k] * (long long)z[k];
                    #pragma unroll
                    for (int off = 32; off; off >>= 1) vs += __shfl_xor(vs, off);
                }
                double std_int = floor(sqrt((double)vs)) * (double)(1 << s);
                if (std_int < 1.0) std_int = 1.0;         // degenerate guard
                long long factor = (long long)floor(2147483648.0 / std_int);
                if (lane == 0) fct[(size_t)(wid * 4 + rr) * 16 + s] = (unsigned)factor;
                float hmn = 3.402823466e38f, hmx = -3.402823466e38f;
                #pragma unroll
                for (int k = 0; k < 12; ++k) {
                    long long t = ((long long)q[k] * factor) >> 1;   // floor(y*factor/2)
                    int v2 = (int)t + t_lnbi[k];
                    float h = (float)v2 * t_sfo[k];
                    hmn = fminf(hmn, h);
                    hmx = fmaxf(hmx, h);
                }
                #pragma unroll
                for (int off = 32; off; off >>= 1) {
                    hmn = fminf(hmn, __shfl_xor(hmn, off));
                    hmx = fmaxf(hmx, __shfl_xor(hmx, off));
                }
                if (lane == 0) {
                    unsigned e = fenc(hmn);
                    if (e < cmi[s]) atomicMin((unsigned*)&cmi[s], e);   // guarded, monotone
                    e = fenc(hmx);
                    if (e > cma[s]) atomicMax((unsigned*)&cma[s], e);
                }
            }
            #pragma unroll
            for (int k = 0; k < 12; ++k) z[k] >>= 1;
        }
        #pragma unroll
        for (int c = 0; c < 3; ++c) { aP[c] = aN[c]; xP[c] = xN[c]; }
    }
    if (lane == 0) {
        int* sc = (int*)(ws + SC_OFF);
        if (locMax > 0 && locMax > *(volatile int*)(sc + 4)) atomicMax(sc + 4, locMax);
        if (locMin < *(volatile int*)(sc + 8)) atomicMin(sc + 8, locMin);
    }
}

// ============ K5A: window-sufficiency flag ============
__global__ void k5a_flag(char* __restrict__ ws) {
    if (threadIdx.x == 0) {
        int S = ((const int*)(ws + SC_OFF))[4];
        int smin = ((const int*)(ws + SC_OFF))[8];
        ((int*)(ws + SC_OFF))[9] = (S - smin > 3) ? 1 : 0;
    }
}

// ============ K4FB: exact fallback -- full single-candidate pass at shift S ============
// Runs only if some row's window missed S (flag!=0). Idempotent with k3f's
// writes (same factor values; monotone atomics).
__global__ __launch_bounds__(256) void k4_fb(char* __restrict__ ws, const int* __restrict__ buf) {
    if (*((volatile int*)(ws + SC_OFF) + 9) == 0) return;   // common path: ~free
    int tid = threadIdx.x, lane = tid & 63, wave = tid >> 6;
    int wid = blockIdx.x * 4 + wave;
    int S = ((const int*)(ws + SC_OFF))[4];
    const int* lnbi = (const int*)(ws + LNBI_OFF);
    const float* sfo = (const float*)(ws + SFO_OFF);
    unsigned* fct = (unsigned*)(ws + FCT_OFF);
    volatile unsigned* cmi = (volatile unsigned*)(ws + CMIN_OFF);
    volatile unsigned* cma = (volatile unsigned*)(ws + CMAX_OFF);
    int t_lnbi[12]; float t_sfo[12];
    #pragma unroll
    for (int c = 0; c < 3; ++c) {
        int o0 = (lane + 64 * c) * 4;
        #pragma unroll
        for (int j = 0; j < 4; ++j) { t_lnbi[c * 4 + j] = lnbi[o0 + j]; t_sfo[c * 4 + j] = sfo[o0 + j]; }
    }
    for (int rr = 0; rr < 4; ++rr) {
        size_t base = (size_t)(wid * 4 + rr) * HDIM;
        int yv[12];
        #pragma unroll
        for (int c = 0; c < 3; ++c) {
            int4 y4 = ((const int4*)(buf + base))[lane + 64 * c];
            yv[c * 4 + 0] = y4.x; yv[c * 4 + 1] = y4.y; yv[c * 4 + 2] = y4.z; yv[c * 4 + 3] = y4.w;
        }
        long long vs = 0;
        #pragma unroll
        for (int k = 0; k < 12; ++k) { int zz = yv[k] >> S; vs += (long long)zz * (long long)zz; }
        #pragma unroll
        for (int off = 32; off; off >>= 1) vs += __shfl_xor(vs, off);
        double std_int = floor(sqrt((double)vs)) * (double)(1 << S);
        if (std_int < 1.0) std_int = 1.0;
        long long factor = (long long)floor(2147483648.0 / std_int);
        if (lane == 0) fct[(size_t)(wid * 4 + rr) * 16 + S] = (unsigned)factor;
        float hmn = 3.402823466e38f, hmx = -3.402823466e38f;
        #pragma unroll
        for (int k = 0; k < 12; ++k) {
            long long t = ((long long)yv[k] * factor) >> 1;
            int v2 = (int)t + t_lnbi[k];
            float h = (float)v2 * t_sfo[k];
            hmn = fminf(hmn, h);
            hmx = fmaxf(hmx, h);
        }
        #pragma unroll
        for (int off = 32; off; off >>= 1) {
            hmn = fminf(hmn, __shfl_xor(hmn, off));
            hmx = fmaxf(hmx, __shfl_xor(hmx, off));
        }
        if (lane == 0) {
            unsigned e = fenc(hmn);
            if (e < cmi[S]) atomicMin((unsigned*)&cmi[S], e);
            e = fenc(hmx);
            if (e > cma[S]) atomicMax((unsigned*)&cma[S], e);
        }
    }
}

// ============ K5: select candidate for global shift -> s2 + rs2 table ============
__global__ __launch_bounds__(256) void k5_scale2(char* __restrict__ ws) {
    __shared__ float s_sh;
    if (threadIdx.x == 0) {
        int shift = ((const int*)(ws + SC_OFF))[4];
        float mn = fdec(((const unsigned*)(ws + CMIN_OFF))[shift]);
        float mx = fdec(((const unsigned*)(ws + CMAX_OFF))[shift]);
        float s2 = fmaxf(fmaxf(fabsf(mn), fabsf(mx)), 1e-8f) / 127.0f;
        ((float*)(ws + SC_OFF))[6] = s2;
        s_sh = s2;
    }
    __syncthreads();
    float s2 = s_sh;
    const float* sfo = (const float*)(ws + SFO_OFF);
    double* rs2 = (double*)(ws + RS2_OFF);
    for (int o = threadIdx.x; o < HDIM; o += 256) {
        double r = (double)sfo[o] / (double)s2;
        int ex; double mant = frexp(r, &ex);
        double m = floor(mant * 2147483648.0 + 0.5);
        rs2[o] = m * exp2((double)(ex - 31));
    }
}

// ============ K6: LN normalize (factor table @ global shift) + 8-bit requant + output ============
__global__ __launch_bounds__(256) void k6_out(char* __restrict__ ws, float* __restrict__ out) {
    int tid = threadIdx.x, lane = tid & 63, wave = tid >> 6;
    int wid = blockIdx.x * 4 + wave;
    const double* rs2 = (const double*)(ws + RS2_OFF);
    const int* lnbi = (const int*)(ws + LNBI_OFF);
    const unsigned* fct = (const unsigned*)(ws + FCT_OFF);
    int shift = ((const int*)(ws + SC_OFF))[4];
    float s2 = ((const float*)(ws + SC_OFF))[6];
    double t_rs2[12]; int t_lnbi[12];
    #pragma unroll
    for (int c = 0; c < 3; ++c) {
        int o0 = (lane + 64 * c) * 4;
        #pragma unroll
        for (int j = 0; j < 4; ++j) { t_rs2[c * 4 + j] = rs2[o0 + j]; t_lnbi[c * 4 + j] = lnbi[o0 + j]; }
    }
    int* buf = (int*)out;
    int4 yP[3];
    {
        size_t b0 = (size_t)(wid * 4) * HDIM;
        #pragma unroll
        for (int c = 0; c < 3; ++c) yP[c] = ((const int4*)(buf + b0))[lane + 64 * c];
    }
    for (int rr = 0; rr < 4; ++rr) {
        int4 yN[3];
        if (rr < 3) {
            size_t nb = (size_t)(wid * 4 + rr + 1) * HDIM;
            #pragma unroll
            for (int c = 0; c < 3; ++c) yN[c] = ((const int4*)(buf + nb))[lane + 64 * c];
        }
        size_t base = (size_t)(wid * 4 + rr) * HDIM;
        long long factor = (long long)fct[(size_t)(wid * 4 + rr) * 16 + shift];
        int yv[12];
        #pragma unroll
        for (int c = 0; c < 3; ++c) {
            yv[c * 4 + 0] = yP[c].x; yv[c * 4 + 1] = yP[c].y; yv[c * 4 + 2] = yP[c].z; yv[c * 4 + 3] = yP[c].w;
        }
        #pragma unroll
        for (int c = 0; c < 3; ++c) {
            float4 r;
            float* rp = &r.x;
            #pragma unroll
            for (int j = 0; j < 4; ++j) {
                int k = c * 4 + j;
                long long t = ((long long)yv[k] * factor) >> 1;   // identical to k3f/k4_fb
                int v2 = (int)t + t_lnbi[k];
                double q = rint((double)v2 * t_rs2[k]);
                q = fmin(fmax(q, -128.0), 127.0);
                rp[j] = (float)q * s2;
            }
            ((float4*)(out + base))[lane + 64 * c] = r;
        }
        #pragma unroll
        for (int c = 0; c < 3; ++c) yP[c] = yN[c];
    }
    if (wid == 0 && tid == 0) out[(size_t)NTOK * HDIM] = s2;
}

extern "C" void kernel_launch(void* const* d_in, const int* in_sizes, int n_in,
                              void* d_out, int out_size, void* d_ws, size_t ws_size,
                              hipStream_t stream) {
    const float* hs   = (const float*)d_in[0];
    const float* phsf = (const float*)d_in[1];
    const float* inp  = (const float*)d_in[2];
    const float* pisf = (const float*)d_in[3];
    const float* W    = (const float*)d_in[4];
    const float* bias = (const float*)d_in[5];
    const float* ln_w = (const float*)d_in[6];
    const float* ln_b = (const float*)d_in[7];
    char* ws = (char*)d_ws;
    float* out = (float*)d_out;
    int* buf = (int*)d_out;   // d_out doubles as the 100MB int32 intermediate buffer

    k0_prep<<<HDIM, 256, 0, stream>>>(W, bias, ln_w, ln_b, phsf, ws);
    kp_a8<<<NTOK * HDIM / 4096, 256, 0, stream>>>(hs, phsf, ws);
    k1_gemm<<<(NTOK / BM) * (HDIM / BN), 256, 0, stream>>>(inp, ws, buf);
    k2_scale1<<<1, 256, 0, stream>>>(pisf, ws);
    k3f<<<NTOK / 16, 256, 0, stream>>>(ws, buf, inp, pisf);
    k5a_flag<<<1, 64, 0, stream>>>(ws);
    k4_fb<<<NTOK / 16, 256, 0, stream>>>(ws, buf);
    k5_scale2<<<1, 256, 0, stream>>>(ws);
    k6_out<<<NTOK / 16, 256, 0, stream>>>(ws, out);
}

// Round 10
// 420.707 us; speedup vs baseline: 1.3644x; 1.3644x over previous
//
#include <hip/hip_runtime.h>

typedef int   v4i   __attribute__((ext_vector_type(4)));
typedef unsigned long u64x2 __attribute__((ext_vector_type(2)));

#define HDIM 768
#define NTOK 32768

// ---- workspace layout (bytes) ----
static constexpr size_t WX_OFF   = 0;                   // int8 A8 [NTOK*HDIM]
static constexpr size_t WINT_OFF = 25165824;            // int8 W8 [HDIM*HDIM]
static constexpr size_t RS1_OFF  = WINT_OFF + 1179648;  // double[768]
static constexpr size_t RS2_OFF  = RS1_OFF + 6144;      // double[768]
static constexpr size_t BS_OFF   = RS2_OFF + 6144;      // float [768] bias_scale
static constexpr size_t BINT_OFF = BS_OFF + 3072;       // int   [768] b_int
static constexpr size_t LNBI_OFF = BINT_OFF + 3072;     // int   [768] LN bias_int
static constexpr size_t SFO_OFF  = LNBI_OFF + 3072;     // float [768] sf_out
static constexpr size_t SC_OFF   = SFO_OFF + 3072;      // [0]min1 [1]max1 [4]shift [5]s [6]s2 [8]srmin [9]flag
static constexpr size_t RSM1_OFF = SC_OFF + 64;         // double rs_m1
static constexpr size_t CMIN_OFF = SC_OFF + 128;        // uint[16] per-candidate encoded min
static constexpr size_t CMAX_OFF = SC_OFF + 192;        // uint[16] per-candidate encoded max
static constexpr size_t FCT_OFF  = SC_OFF + 256;        // uint[NTOK*16] per-row per-candidate factor (2 MB)

// sortable-uint encoding of float for atomic min/max
__device__ __forceinline__ unsigned fenc(float f) {
    unsigned u = __float_as_uint(f);
    return (u >> 31) ? ~u : (u | 0x80000000u);
}
__device__ __forceinline__ float fdec(unsigned e) {
    unsigned u = (e >> 31) ? (e & 0x7fffffffu) : ~e;
    return __uint_as_float(u);
}

// async global->LDS, 16B per lane; LDS base wave-uniform (HW adds lane*16)
#define GLDS16(g, l) __builtin_amdgcn_global_load_lds( \
    (const __attribute__((address_space(1))) unsigned int*)(g), \
    (__attribute__((address_space(3))) unsigned int*)(l), 16, 0, 0)

// 16B-chunk XOR swizzle within a 64B row: 2-way-only bank aliasing (free).
__device__ __forceinline__ int swz4(int r) { return (r & 3) ^ ((r >> 2) & 3); }

// ============ K0: weight quantization + per-channel tables + scalar init ============
__global__ __launch_bounds__(256) void k0_prep(const float* __restrict__ W,
                                               const float* __restrict__ bias,
                                               const float* __restrict__ ln_w,
                                               const float* __restrict__ ln_b,
                                               const float* __restrict__ phsf,
                                               char* __restrict__ ws) {
    int o = blockIdx.x, tid = threadIdx.x;
    __shared__ float red[256];
    __shared__ float fc_sh;
    float m = 0.f;
    for (int j = tid; j < HDIM; j += 256) m = fmaxf(m, fabsf(W[(size_t)o * HDIM + j]));
    red[tid] = m;
    __syncthreads();
    for (int s = 128; s; s >>= 1) { if (tid < s) red[tid] = fmaxf(red[tid], red[tid + s]); __syncthreads(); }
    if (tid == 0) {
        float fc = fmaxf(red[0], 1e-8f) / 127.0f;     // _sym_scale(8,...)
        float hsf = *phsf;
        float bs = fc * hsf;
        fc_sh = fc;
        ((float*)(ws + BS_OFF))[o] = bs;
        ((int*)(ws + BINT_OFF))[o] = (int)rintf(bias[o] / bs);   // _sym_quant(bias,32)
        float sf = sqrtf(768.0f) / 1073741824.0f;                // sqrt(H)/2^30
        float lw = ln_w[o], lb = ln_b[o];
        ((int*)(ws + LNBI_OFF))[o] = (int)floorf((lb / lw) / sf);
        ((float*)(ws + SFO_OFF))[o] = sf * lw;
    }
    __syncthreads();
    float fc = fc_sh;
    char* w8 = (char*)(ws + WINT_OFF);
    for (int j = tid; j < HDIM; j += 256) {
        float q = rintf(W[(size_t)o * HDIM + j] / fc);
        q = fminf(fmaxf(q, -127.f), 126.f);           // clip [-n, n-1]
        w8[(size_t)o * HDIM + j] = (char)q;
    }
    if (blockIdx.x == 0) {
        if (tid < 16) {
            unsigned* sc = (unsigned*)(ws + SC_OFF);
            unsigned v = 0u;
            if (tid == 0 || tid == 2) v = 0xFFFFFFFFu;    // min slots
            if (tid == 8) v = 127u;                       // srmin init
            sc[tid] = v;                                   // shift/flag/etc -> 0
        }
        if (tid >= 32 && tid < 48) {
            ((unsigned*)(ws + CMIN_OFF))[tid - 32] = 0xFFFFFFFFu;
            ((unsigned*)(ws + CMAX_OFF))[tid - 32] = 0u;
        }
    }
}

// ============ KP: hs -> int8, fully coalesced ============
__global__ __launch_bounds__(256) void kp_a8(const float* __restrict__ hs,
                                             const float* __restrict__ phsf,
                                             char* __restrict__ ws) {
    int tid = threadIdx.x;
    size_t b4 = (size_t)blockIdx.x * 1024 + tid;   // float4 slot
    float inv = 1.0f / *phsf;
    const float4* in4 = (const float4*)hs;
    unsigned* o32 = (unsigned*)(ws + WX_OFF);
    #pragma unroll
    for (int j = 0; j < 4; ++j) {
        float4 v = in4[b4 + j * 256];
        int q0 = (int)rintf(v.x * inv), q1 = (int)rintf(v.y * inv);
        int q2 = (int)rintf(v.z * inv), q3 = (int)rintf(v.w * inv);
        o32[b4 + j * 256] = (unsigned)(q0 & 255) | ((unsigned)(q1 & 255) << 8) |
                            ((unsigned)(q2 & 255) << 16) | ((unsigned)(q3 & 255) << 24);
    }
}

// ============ K1: int8 MFMA GEMM, BM=BN=128 BK=64, counted-vmcnt pipeline ============
#define BM 128
#define BN 128
#define BK 64
#define NKT (HDIM / BK)   // 12
#define SROW 132          // padded LDS row stride (ints) for the epilogue bounce
__global__ __launch_bounds__(256, 3) void k1_gemm(const float* __restrict__ inp,
                                                  char* __restrict__ ws,
                                                  int* __restrict__ accOut) {
    __shared__ alignas(16) char smem[32800];
    char* As0 = smem;                  // 2 x 8192
    char* Bs0 = smem + 16384;          // 2 x 8192
    float* rmn = (float*)(smem + 32768);
    float* rmx = rmn + 4;
    int tid = threadIdx.x, lane = tid & 63, wave = tid >> 6;
    int wrow = lane & 15, g = lane >> 4;
    int bid = blockIdx.x;
    int xcd = bid & 7, slot = bid >> 3;           // 1536 blocks: 8 XCDs x 192 slots
    int mtile = xcd * 32 + slot / 6;
    int ntile = slot % 6;
    int t0 = mtile * BM, o0 = ntile * BN;
    const char* a8 = (const char*)(ws + WX_OFF);
    const char* w8 = (const char*)(ws + WINT_OFF);

    const char* asrc[2]; const char* bsrc[2];
    int ldso[2];
    #pragma unroll
    for (int i = 0; i < 2; ++i) {
        int c = i * 256 + tid, r = c >> 2, s = c & 3;
        asrc[i] = a8 + (size_t)(t0 + r) * HDIM + (s ^ swz4(r)) * 16;
        bsrc[i] = w8 + (size_t)(o0 + r) * HDIM + (s ^ swz4(r)) * 16;
        ldso[i] = (i * 256 + wave * 64) * 16;
    }

    int wm = wave & 1, wn = wave >> 1;            // wave tile: 64(t) x 64(o)
    int aofs[4], bofs[4];
    #pragma unroll
    for (int mi = 0; mi < 4; ++mi) { int r = wm * 64 + mi * 16 + wrow; aofs[mi] = r * BK + ((g ^ swz4(r)) * 16); }
    #pragma unroll
    for (int nf = 0; nf < 4; ++nf) { int r = wn * 64 + nf * 16 + wrow; bofs[nf] = r * BK + ((g ^ swz4(r)) * 16); }

    #pragma unroll
    for (int i = 0; i < 2; ++i) GLDS16(asrc[i], As0 + ldso[i]);
    #pragma unroll
    for (int i = 0; i < 2; ++i) GLDS16(bsrc[i], Bs0 + ldso[i]);
    #pragma unroll
    for (int i = 0; i < 2; ++i) GLDS16(asrc[i] + BK, As0 + 8192 + ldso[i]);
    #pragma unroll
    for (int i = 0; i < 2; ++i) GLDS16(bsrc[i] + BK, Bs0 + 8192 + ldso[i]);
    asm volatile("s_waitcnt vmcnt(4)" ::: "memory");
    __builtin_amdgcn_s_barrier();

    v4i acc[4][4] = {};
    for (int kt = 0; kt < NKT; ++kt) {
        int cur = kt & 1;
        const char* Ac = As0 + cur * 8192;
        const char* Bc = Bs0 + cur * 8192;
        u64x2 af[4], bf[4];
        #pragma unroll
        for (int mi = 0; mi < 4; ++mi) af[mi] = *(const u64x2*)(Ac + aofs[mi]);
        #pragma unroll
        for (int nf = 0; nf < 4; ++nf) bf[nf] = *(const u64x2*)(Bc + bofs[nf]);
        asm volatile("s_waitcnt lgkmcnt(0)" ::: "memory");
        __builtin_amdgcn_s_barrier();
        if (kt + 2 < NKT) {
            #pragma unroll
            for (int i = 0; i < 2; ++i) GLDS16(asrc[i] + (kt + 2) * BK, As0 + cur * 8192 + ldso[i]);
            #pragma unroll
            for (int i = 0; i < 2; ++i) GLDS16(bsrc[i] + (kt + 2) * BK, Bs0 + cur * 8192 + ldso[i]);
        }
        __builtin_amdgcn_s_setprio(1);
        #pragma unroll
        for (int mi = 0; mi < 4; ++mi)
            #pragma unroll
            for (int nf = 0; nf < 4; ++nf) {
                acc[mi][nf] = __builtin_amdgcn_mfma_i32_16x16x32_i8((long)af[mi][0], (long)bf[nf][0], acc[mi][nf], 0, 0, 0);
                acc[mi][nf] = __builtin_amdgcn_mfma_i32_16x16x32_i8((long)af[mi][1], (long)bf[nf][1], acc[mi][nf], 0, 0, 0);
            }
        __builtin_amdgcn_s_setprio(0);
        if (kt + 2 < NKT) {
            asm volatile("s_waitcnt vmcnt(4)" ::: "memory");
            __builtin_amdgcn_s_barrier();
        } else if (kt + 2 == NKT) {
            asm volatile("s_waitcnt vmcnt(0)" ::: "memory");
            __builtin_amdgcn_s_barrier();
        }
    }

    // ---- epilogue: LDS-bounce per mi-slice, vectorized 16B global I/O ----
    const float* bscale = (const float*)(ws + BS_OFF);
    const int* bint = (const int*)(ws + BINT_OFF);
    int* sAcc = (int*)smem;
    float lmn = 3.402823466e38f, lmx = -3.402823466e38f;
    #pragma unroll
    for (int mi = 0; mi < 4; ++mi) {
        __syncthreads();
        #pragma unroll
        for (int nf = 0; nf < 4; ++nf)
            #pragma unroll
            for (int r = 0; r < 4; ++r)
                sAcc[(wm * 16 + g * 4 + r) * SROW + wn * 64 + nf * 16 + wrow] = acc[mi][nf][r];
        __syncthreads();
        #pragma unroll
        for (int k = 0; k < 4; ++k) {
            int i4 = tid + k * 256;                // 1024 int4 = 32 rows x 32 int4
            int sr = i4 >> 5, c4 = i4 & 31;
            int t = t0 + (sr >> 4) * 64 + mi * 16 + (sr & 15);
            int col = o0 + c4 * 4;
            int4 a4 = *(const int4*)&sAcc[sr * SROW + c4 * 4];
            int4 b4 = *(const int4*)&bint[col];
            float4 bs4 = *(const float4*)&bscale[col];
            a4.x += b4.x; a4.y += b4.y; a4.z += b4.z; a4.w += b4.w;
            size_t idx = (size_t)t * HDIM + col;
            *(int4*)&accOut[idx] = a4;
            float4 x4 = *(const float4*)&inp[idx];
            float xa;
            xa = (float)a4.x * bs4.x + x4.x; lmn = fminf(lmn, xa); lmx = fmaxf(lmx, xa);
            xa = (float)a4.y * bs4.y + x4.y; lmn = fminf(lmn, xa); lmx = fmaxf(lmx, xa);
            xa = (float)a4.z * bs4.z + x4.z; lmn = fminf(lmn, xa); lmx = fmaxf(lmx, xa);
            xa = (float)a4.w * bs4.w + x4.w; lmn = fminf(lmn, xa); lmx = fmaxf(lmx, xa);
        }
    }
    #pragma unroll
    for (int off = 32; off; off >>= 1) {
        lmn = fminf(lmn, __shfl_down(lmn, off));
        lmx = fmaxf(lmx, __shfl_down(lmx, off));
    }
    __syncthreads();
    if (lane == 0) { rmn[wave] = lmn; rmx[wave] = lmx; }
    __syncthreads();
    if (tid == 0) {
        float mn = fminf(fminf(rmn[0], rmn[1]), fminf(rmn[2], rmn[3]));
        float mx = fmaxf(fmaxf(rmx[0], rmx[1]), fmaxf(rmx[2], rmx[3]));
        volatile unsigned* sc = (volatile unsigned*)(ws + SC_OFF);
        unsigned emn = fenc(mn), emx = fenc(mx);
        if (emn < sc[0]) atomicMin((unsigned*)&sc[0], emn);
        if (emx > sc[1]) atomicMax((unsigned*)&sc[1], emx);
    }
}

// ============ K2: finalize ln_in_scale s + frexp tables ============
__global__ __launch_bounds__(256) void k2_scale1(const float* __restrict__ pisf, char* __restrict__ ws) {
    __shared__ float s_sh;
    unsigned* sc = (unsigned*)(ws + SC_OFF);
    if (threadIdx.x == 0) {
        float mn = fdec(sc[0]), mx = fdec(sc[1]);
        float s = fmaxf(fmaxf(fabsf(mn), fabsf(mx)), 1e-8f) / 2097151.0f;  // n = 2^21-1
        ((float*)sc)[5] = s;
        s_sh = s;
        double r = (double)(*pisf) / (double)s;
        int ex; double mant = frexp(r, &ex);
        double m1 = floor(mant * 2147483648.0 + 0.5);
        ((double*)(ws + RSM1_OFF))[0] = m1 * exp2((double)(ex - 31));
    }
    __syncthreads();
    float s = s_sh;
    const float* bs = (const float*)(ws + BS_OFF);
    double* rs1 = (double*)(ws + RS1_OFF);
    for (int o = threadIdx.x; o < HDIM; o += 256) {
        double r = (double)bs[o] / (double)s;
        int ex; double mant = frexp(r, &ex);
        double m = floor(mant * 2147483648.0 + 0.5);
        rs1[o] = m * exp2((double)(ex - 31));
    }
}

// ============ K3F: fused requant + LN stats, 4-candidate window, LDS commit ============
// Round-8 lesson: per-row device-scope volatile+atomic pairs serialize the wave
// (284us, all pipes idle). Here per-row candidate min/max commit to a per-wave
// LDS table (runtime s index fine in LDS, wave-exclusive slot); ONE block-level
// guarded-atomic commit at kernel end (round-7 discipline, measured fine).
__global__ __launch_bounds__(256) void k3f(char* __restrict__ ws, int* __restrict__ buf,
                                           const float* __restrict__ inp,
                                           const float* __restrict__ pisf) {
    int tid = threadIdx.x, lane = tid & 63, wave = tid >> 6;
    int wid = blockIdx.x * 4 + wave;
    const double* rs1 = (const double*)(ws + RS1_OFF);
    double rsm1 = *(const double*)(ws + RSM1_OFF);
    float inv_isf = 1.0f / *pisf;
    const int* lnbi = (const int*)(ws + LNBI_OFF);
    const float* sfo = (const float*)(ws + SFO_OFF);
    unsigned* fct = (unsigned*)(ws + FCT_OFF);
    __shared__ float smn[4][16], smx[4][16];
    if (lane < 16) { smn[wave][lane] = 3.402823466e38f; smx[wave][lane] = -3.402823466e38f; }
    double t_rs1[12]; int t_lnbi[12]; float t_sfo[12];
    #pragma unroll
    for (int c = 0; c < 3; ++c) {
        int o0 = (lane + 64 * c) * 4;
        #pragma unroll
        for (int j = 0; j < 4; ++j) {
            t_rs1[c * 4 + j] = rs1[o0 + j];
            t_lnbi[c * 4 + j] = lnbi[o0 + j];
            t_sfo[c * 4 + j] = sfo[o0 + j];
        }
    }
    int locMax = 0, locMin = 127;
    int4 aP[3]; float4 xP[3];
    {
        size_t b0 = (size_t)(wid * 4) * HDIM;
        #pragma unroll
        for (int c = 0; c < 3; ++c) {
            aP[c] = ((const int4*)(buf + b0))[lane + 64 * c];
            xP[c] = ((const float4*)(inp + b0))[lane + 64 * c];
        }
    }
    for (int rr = 0; rr < 4; ++rr) {
        int4 aN[3]; float4 xN[3];
        if (rr < 3) {
            size_t nb = (size_t)(wid * 4 + rr + 1) * HDIM;
            #pragma unroll
            for (int c = 0; c < 3; ++c) {
                aN[c] = ((const int4*)(buf + nb))[lane + 64 * c];
                xN[c] = ((const float4*)(inp + nb))[lane + 64 * c];
            }
        }
        size_t base = (size_t)(wid * 4 + rr) * HDIM;
        int q[12];
        int sum = 0;
        #pragma unroll
        for (int c = 0; c < 3; ++c) {
            int av[4] = {aP[c].x, aP[c].y, aP[c].z, aP[c].w};
            float xv[4] = {xP[c].x, xP[c].y, xP[c].z, xP[c].w};
            #pragma unroll
            for (int j = 0; j < 4; ++j) {
                double q1 = rint((double)av[j] * t_rs1[c * 4 + j]);
                int wxj = (int)rintf(xv[j] * inv_isf);
                double qq = q1 + rint((double)wxj * rsm1);
                qq = fmin(fmax(qq, -2097152.0), 2097151.0);   // clip [-2^21, 2^21-1]
                q[c * 4 + j] = (int)qq;
                sum += q[c * 4 + j];
            }
        }
        #pragma unroll
        for (int off = 32; off; off >>= 1) sum += __shfl_xor(sum, off);
        int mean = (int)rint((double)sum / 768.0);
        long long v0 = 0;
        #pragma unroll
        for (int k = 0; k < 12; ++k) { q[k] -= mean; v0 += (long long)q[k] * (long long)q[k]; }
        #pragma unroll
        for (int off = 32; off; off >>= 1) v0 += __shfl_xor(v0, off);
        #pragma unroll
        for (int c = 0; c < 3; ++c) {
            int4 y = {q[c * 4 + 0], q[c * 4 + 1], q[c * 4 + 2], q[c * 4 + 3]};
            ((int4*)(buf + base))[lane + 64 * c] = y;
        }
        double vd = (double)(v0 < 1 ? 1LL : v0);
        int sr = (int)ceil(0.5 * log2(vd) - 16.0);        // per-row shift, provably <= 11
        if (sr < 0) sr = 0;
        if (sr > 11) sr = 11;
        locMax = max(locMax, sr);
        locMin = min(locMin, sr);
        int z[12];
        #pragma unroll
        for (int k = 0; k < 12; ++k) z[k] = q[k] >> sr;
        #pragma unroll
        for (int d = 0; d < 4; ++d) {                     // candidates s = sr+d (static d)
            int s = sr + d;
            if (s < 12) {                                 // wave-uniform predicate
                long long vs;
                if (d == 0 && sr == 0) vs = v0;
                else {
                    vs = 0;
                    #pragma unroll
                    for (int k = 0; k < 12; ++k) vs += (long long)z[k] * (long long)z[k];
                    #pragma unroll
                    for (int off = 32; off; off >>= 1) vs += __shfl_xor(vs, off);
                }
                double std_int = floor(sqrt((double)vs)) * (double)(1 << s);
                if (std_int < 1.0) std_int = 1.0;         // degenerate guard
                long long factor = (long long)floor(2147483648.0 / std_int);
                if (lane == 0) fct[(size_t)(wid * 4 + rr) * 16 + s] = (unsigned)factor;
                float hmn = 3.402823466e38f, hmx = -3.402823466e38f;
                #pragma unroll
                for (int k = 0; k < 12; ++k) {
                    long long t = ((long long)q[k] * factor) >> 1;   // floor(y*factor/2)
                    int v2 = (int)t + t_lnbi[k];
                    float h = (float)v2 * t_sfo[k];
                    hmn = fminf(hmn, h);
                    hmx = fmaxf(hmx, h);
                }
                #pragma unroll
                for (int off = 32; off; off >>= 1) {
                    hmn = fminf(hmn, __shfl_xor(hmn, off));
                    hmx = fmaxf(hmx, __shfl_xor(hmx, off));
                }
                if (lane == 0) {                          // LDS commit: cheap, wave-local
                    smn[wave][s] = fminf(smn[wave][s], hmn);
                    smx[wave][s] = fmaxf(smx[wave][s], hmx);
                }
            }
            #pragma unroll
            for (int k = 0; k < 12; ++k) z[k] >>= 1;
        }
        #pragma unroll
        for (int c = 0; c < 3; ++c) { aP[c] = aN[c]; xP[c] = xN[c]; }
    }
    if (lane == 0) {
        int* sc = (int*)(ws + SC_OFF);
        if (locMax > 0 && locMax > *(volatile int*)(sc + 4)) atomicMax(sc + 4, locMax);
        if (locMin < *(volatile int*)(sc + 8)) atomicMin(sc + 8, locMin);
    }
    // ---- end-of-block commit: reduce LDS across waves, guarded global atomics ----
    __syncthreads();
    if (tid < 16) {
        float mn = fminf(fminf(smn[0][tid], smn[1][tid]), fminf(smn[2][tid], smn[3][tid]));
        float mx = fmaxf(fmaxf(smx[0][tid], smx[1][tid]), fmaxf(smx[2][tid], smx[3][tid]));
        if (mn < 3.3e38f) {
            volatile unsigned* cmi = (volatile unsigned*)(ws + CMIN_OFF);
            unsigned e = fenc(mn);
            if (e < cmi[tid]) atomicMin((unsigned*)&cmi[tid], e);
        }
        if (mx > -3.3e38f) {
            volatile unsigned* cma = (volatile unsigned*)(ws + CMAX_OFF);
            unsigned e = fenc(mx);
            if (e > cma[tid]) atomicMax((unsigned*)&cma[tid], e);
        }
    }
}

// ============ K5A: window-sufficiency flag ============
__global__ void k5a_flag(char* __restrict__ ws) {
    if (threadIdx.x == 0) {
        int S = ((const int*)(ws + SC_OFF))[4];
        int smin = ((const int*)(ws + SC_OFF))[8];
        ((int*)(ws + SC_OFF))[9] = (S - smin > 3) ? 1 : 0;
    }
}

// ============ K4FB: exact fallback -- full single-candidate pass at shift S ============
__global__ __launch_bounds__(256) void k4_fb(char* __restrict__ ws, const int* __restrict__ buf) {
    if (*((volatile int*)(ws + SC_OFF) + 9) == 0) return;   // common path: ~free
    int tid = threadIdx.x, lane = tid & 63, wave = tid >> 6;
    int wid = blockIdx.x * 4 + wave;
    int S = ((const int*)(ws + SC_OFF))[4];
    const int* lnbi = (const int*)(ws + LNBI_OFF);
    const float* sfo = (const float*)(ws + SFO_OFF);
    unsigned* fct = (unsigned*)(ws + FCT_OFF);
    volatile unsigned* cmi = (volatile unsigned*)(ws + CMIN_OFF);
    volatile unsigned* cma = (volatile unsigned*)(ws + CMAX_OFF);
    int t_lnbi[12]; float t_sfo[12];
    #pragma unroll
    for (int c = 0; c < 3; ++c) {
        int o0 = (lane + 64 * c) * 4;
        #pragma unroll
        for (int j = 0; j < 4; ++j) { t_lnbi[c * 4 + j] = lnbi[o0 + j]; t_sfo[c * 4 + j] = sfo[o0 + j]; }
    }
    for (int rr = 0; rr < 4; ++rr) {
        size_t base = (size_t)(wid * 4 + rr) * HDIM;
        int yv[12];
        #pragma unroll
        for (int c = 0; c < 3; ++c) {
            int4 y4 = ((const int4*)(buf + base))[lane + 64 * c];
            yv[c * 4 + 0] = y4.x; yv[c * 4 + 1] = y4.y; yv[c * 4 + 2] = y4.z; yv[c * 4 + 3] = y4.w;
        }
        long long vs = 0;
        #pragma unroll
        for (int k = 0; k < 12; ++k) { int zz = yv[k] >> S; vs += (long long)zz * (long long)zz; }
        #pragma unroll
        for (int off = 32; off; off >>= 1) vs += __shfl_xor(vs, off);
        double std_int = floor(sqrt((double)vs)) * (double)(1 << S);
        if (std_int < 1.0) std_int = 1.0;
        long long factor = (long long)floor(2147483648.0 / std_int);
        if (lane == 0) fct[(size_t)(wid * 4 + rr) * 16 + S] = (unsigned)factor;
        float hmn = 3.402823466e38f, hmx = -3.402823466e38f;
        #pragma unroll
        for (int k = 0; k < 12; ++k) {
            long long t = ((long long)yv[k] * factor) >> 1;
            int v2 = (int)t + t_lnbi[k];
            float h = (float)v2 * t_sfo[k];
            hmn = fminf(hmn, h);
            hmx = fmaxf(hmx, h);
        }
        #pragma unroll
        for (int off = 32; off; off >>= 1) {
            hmn = fminf(hmn, __shfl_xor(hmn, off));
            hmx = fmaxf(hmx, __shfl_xor(hmx, off));
        }
        if (lane == 0) {
            unsigned e = fenc(hmn);
            if (e < cmi[S]) atomicMin((unsigned*)&cmi[S], e);
            e = fenc(hmx);
            if (e > cma[S]) atomicMax((unsigned*)&cma[S], e);
        }
    }
}

// ============ K5: select candidate for global shift -> s2 + rs2 table ============
__global__ __launch_bounds__(256) void k5_scale2(char* __restrict__ ws) {
    __shared__ float s_sh;
    if (threadIdx.x == 0) {
        int shift = ((const int*)(ws + SC_OFF))[4];
        float mn = fdec(((const unsigned*)(ws + CMIN_OFF))[shift]);
        float mx = fdec(((const unsigned*)(ws + CMAX_OFF))[shift]);
        float s2 = fmaxf(fmaxf(fabsf(mn), fabsf(mx)), 1e-8f) / 127.0f;
        ((float*)(ws + SC_OFF))[6] = s2;
        s_sh = s2;
    }
    __syncthreads();
    float s2 = s_sh;
    const float* sfo = (const float*)(ws + SFO_OFF);
    double* rs2 = (double*)(ws + RS2_OFF);
    for (int o = threadIdx.x; o < HDIM; o += 256) {
        double r = (double)sfo[o] / (double)s2;
        int ex; double mant = frexp(r, &ex);
        double m = floor(mant * 2147483648.0 + 0.5);
        rs2[o] = m * exp2((double)(ex - 31));
    }
}

// ============ K6: LN normalize (factor table @ global shift) + 8-bit requant + output ============
__global__ __launch_bounds__(256) void k6_out(char* __restrict__ ws, float* __restrict__ out) {
    int tid = threadIdx.x, lane = tid & 63, wave = tid >> 6;
    int wid = blockIdx.x * 4 + wave;
    const double* rs2 = (const double*)(ws + RS2_OFF);
    const int* lnbi = (const int*)(ws + LNBI_OFF);
    const unsigned* fct = (const unsigned*)(ws + FCT_OFF);
    int shift = ((const int*)(ws + SC_OFF))[4];
    float s2 = ((const float*)(ws + SC_OFF))[6];
    double t_rs2[12]; int t_lnbi[12];
    #pragma unroll
    for (int c = 0; c < 3; ++c) {
        int o0 = (lane + 64 * c) * 4;
        #pragma unroll
        for (int j = 0; j < 4; ++j) { t_rs2[c * 4 + j] = rs2[o0 + j]; t_lnbi[c * 4 + j] = lnbi[o0 + j]; }
    }
    int* buf = (int*)out;
    int4 yP[3];
    {
        size_t b0 = (size_t)(wid * 4) * HDIM;
        #pragma unroll
        for (int c = 0; c < 3; ++c) yP[c] = ((const int4*)(buf + b0))[lane + 64 * c];
    }
    for (int rr = 0; rr < 4; ++rr) {
        int4 yN[3];
        if (rr < 3) {
            size_t nb = (size_t)(wid * 4 + rr + 1) * HDIM;
            #pragma unroll
            for (int c = 0; c < 3; ++c) yN[c] = ((const int4*)(buf + nb))[lane + 64 * c];
        }
        size_t base = (size_t)(wid * 4 + rr) * HDIM;
        long long factor = (long long)fct[(size_t)(wid * 4 + rr) * 16 + shift];
        int yv[12];
        #pragma unroll
        for (int c = 0; c < 3; ++c) {
            yv[c * 4 + 0] = yP[c].x; yv[c * 4 + 1] = yP[c].y; yv[c * 4 + 2] = yP[c].z; yv[c * 4 + 3] = yP[c].w;
        }
        #pragma unroll
        for (int c = 0; c < 3; ++c) {
            float4 r;
            float* rp = &r.x;
            #pragma unroll
            for (int j = 0; j < 4; ++j) {
                int k = c * 4 + j;
                long long t = ((long long)yv[k] * factor) >> 1;   // identical to k3f/k4_fb
                int v2 = (int)t + t_lnbi[k];
                double q = rint((double)v2 * t_rs2[k]);
                q = fmin(fmax(q, -128.0), 127.0);
                rp[j] = (float)q * s2;
            }
            ((float4*)(out + base))[lane + 64 * c] = r;
        }
        #pragma unroll
        for (int c = 0; c < 3; ++c) yP[c] = yN[c];
    }
    if (wid == 0 && tid == 0) out[(size_t)NTOK * HDIM] = s2;
}

extern "C" void kernel_launch(void* const* d_in, const int* in_sizes, int n_in,
                              void* d_out, int out_size, void* d_ws, size_t ws_size,
                              hipStream_t stream) {
    const float* hs   = (const float*)d_in[0];
    const float* phsf = (const float*)d_in[1];
    const float* inp  = (const float*)d_in[2];
    const float* pisf = (const float*)d_in[3];
    const float* W    = (const float*)d_in[4];
    const float* bias = (const float*)d_in[5];
    const float* ln_w = (const float*)d_in[6];
    const float* ln_b = (const float*)d_in[7];
    char* ws = (char*)d_ws;
    float* out = (float*)d_out;
    int* buf = (int*)d_out;   // d_out doubles as the 100MB int32 intermediate buffer

    k0_prep<<<HDIM, 256, 0, stream>>>(W, bias, ln_w, ln_b, phsf, ws);
    kp_a8<<<NTOK * HDIM / 4096, 256, 0, stream>>>(hs, phsf, ws);
    k1_gemm<<<(NTOK / BM) * (HDIM / BN), 256, 0, stream>>>(inp, ws, buf);
    k2_scale1<<<1, 256, 0, stream>>>(pisf, ws);
    k3f<<<NTOK / 16, 256, 0, stream>>>(ws, buf, inp, pisf);
    k5a_flag<<<1, 64, 0, stream>>>(ws);
    k4_fb<<<NTOK / 16, 256, 0, stream>>>(ws, buf);
    k5_scale2<<<1, 256, 0, stream>>>(ws);
    k6_out<<<NTOK / 16, 256, 0, stream>>>(ws, out);
}

// Round 11
// 415.189 us; speedup vs baseline: 1.3825x; 1.0133x over previous
//
#include <hip/hip_runtime.h>

typedef int   v4i   __attribute__((ext_vector_type(4)));
typedef unsigned long u64x2 __attribute__((ext_vector_type(2)));

#define HDIM 768
#define NTOK 32768

// ---- workspace layout (bytes) ----
static constexpr size_t WX_OFF   = 0;                   // int8 A8 [NTOK*HDIM]
static constexpr size_t WINT_OFF = 25165824;            // int8 W8 [HDIM*HDIM]
static constexpr size_t RS1_OFF  = WINT_OFF + 1179648;  // double[768]
static constexpr size_t RS2_OFF  = RS1_OFF + 6144;      // double[768]
static constexpr size_t BS_OFF   = RS2_OFF + 6144;      // float [768] bias_scale
static constexpr size_t BINT_OFF = BS_OFF + 3072;       // int   [768] b_int
static constexpr size_t LNBI_OFF = BINT_OFF + 3072;     // int   [768] LN bias_int
static constexpr size_t SFO_OFF  = LNBI_OFF + 3072;     // float [768] sf_out
static constexpr size_t SC_OFF   = SFO_OFF + 3072;      // [0]min1 [1]max1 [4]shift [5]s [6]s2 [8]srmin [9]flag
static constexpr size_t RSM1_OFF = SC_OFF + 64;         // double rs_m1
static constexpr size_t CMIN_OFF = SC_OFF + 128;        // uint[16] per-candidate encoded min
static constexpr size_t CMAX_OFF = SC_OFF + 192;        // uint[16] per-candidate encoded max
static constexpr size_t FCT_OFF  = SC_OFF + 256;        // uint[NTOK*16] per-row per-candidate factor (2 MB)

// sortable-uint encoding of float for atomic min/max
__device__ __forceinline__ unsigned fenc(float f) {
    unsigned u = __float_as_uint(f);
    return (u >> 31) ? ~u : (u | 0x80000000u);
}
__device__ __forceinline__ float fdec(unsigned e) {
    unsigned u = (e >> 31) ? (e & 0x7fffffffu) : ~e;
    return __uint_as_float(u);
}

// async global->LDS, 16B per lane; LDS base wave-uniform (HW adds lane*16)
#define GLDS16(g, l) __builtin_amdgcn_global_load_lds( \
    (const __attribute__((address_space(1))) unsigned int*)(g), \
    (__attribute__((address_space(3))) unsigned int*)(l), 16, 0, 0)

// 16B-chunk XOR swizzle within a 64B row: 2-way-only bank aliasing (free).
__device__ __forceinline__ int swz4(int r) { return (r & 3) ^ ((r >> 2) & 3); }

// ============ K0: weight quantization + per-channel tables + scalar init ============
__global__ __launch_bounds__(256) void k0_prep(const float* __restrict__ W,
                                               const float* __restrict__ bias,
                                               const float* __restrict__ ln_w,
                                               const float* __restrict__ ln_b,
                                               const float* __restrict__ phsf,
                                               char* __restrict__ ws) {
    int o = blockIdx.x, tid = threadIdx.x;
    __shared__ float red[256];
    __shared__ float fc_sh;
    float m = 0.f;
    for (int j = tid; j < HDIM; j += 256) m = fmaxf(m, fabsf(W[(size_t)o * HDIM + j]));
    red[tid] = m;
    __syncthreads();
    for (int s = 128; s; s >>= 1) { if (tid < s) red[tid] = fmaxf(red[tid], red[tid + s]); __syncthreads(); }
    if (tid == 0) {
        float fc = fmaxf(red[0], 1e-8f) / 127.0f;     // _sym_scale(8,...)
        float hsf = *phsf;
        float bs = fc * hsf;
        fc_sh = fc;
        ((float*)(ws + BS_OFF))[o] = bs;
        ((int*)(ws + BINT_OFF))[o] = (int)rintf(bias[o] / bs);   // _sym_quant(bias,32)
        float sf = sqrtf(768.0f) / 1073741824.0f;                // sqrt(H)/2^30
        float lw = ln_w[o], lb = ln_b[o];
        ((int*)(ws + LNBI_OFF))[o] = (int)floorf((lb / lw) / sf);
        ((float*)(ws + SFO_OFF))[o] = sf * lw;
    }
    __syncthreads();
    float fc = fc_sh;
    char* w8 = (char*)(ws + WINT_OFF);
    for (int j = tid; j < HDIM; j += 256) {
        float q = rintf(W[(size_t)o * HDIM + j] / fc);
        q = fminf(fmaxf(q, -127.f), 126.f);           // clip [-n, n-1]
        w8[(size_t)o * HDIM + j] = (char)q;
    }
    if (blockIdx.x == 0) {
        if (tid < 16) {
            unsigned* sc = (unsigned*)(ws + SC_OFF);
            unsigned v = 0u;
            if (tid == 0 || tid == 2) v = 0xFFFFFFFFu;    // min slots
            if (tid == 8) v = 127u;                       // srmin init
            sc[tid] = v;                                   // shift/flag/etc -> 0
        }
        if (tid >= 32 && tid < 48) {
            ((unsigned*)(ws + CMIN_OFF))[tid - 32] = 0xFFFFFFFFu;
            ((unsigned*)(ws + CMAX_OFF))[tid - 32] = 0u;
        }
    }
}

// ============ KP: hs -> int8, fully coalesced ============
__global__ __launch_bounds__(256) void kp_a8(const float* __restrict__ hs,
                                             const float* __restrict__ phsf,
                                             char* __restrict__ ws) {
    int tid = threadIdx.x;
    size_t b4 = (size_t)blockIdx.x * 1024 + tid;   // float4 slot
    float inv = 1.0f / *phsf;
    const float4* in4 = (const float4*)hs;
    unsigned* o32 = (unsigned*)(ws + WX_OFF);
    #pragma unroll
    for (int j = 0; j < 4; ++j) {
        float4 v = in4[b4 + j * 256];
        int q0 = (int)rintf(v.x * inv), q1 = (int)rintf(v.y * inv);
        int q2 = (int)rintf(v.z * inv), q3 = (int)rintf(v.w * inv);
        o32[b4 + j * 256] = (unsigned)(q0 & 255) | ((unsigned)(q1 & 255) << 8) |
                            ((unsigned)(q2 & 255) << 16) | ((unsigned)(q3 & 255) << 24);
    }
}

// ============ K1: int8 MFMA GEMM, BM=BN=128 BK=64, counted-vmcnt pipeline ============
#define BM 128
#define BN 128
#define BK 64
#define NKT (HDIM / BK)   // 12
#define SROW 132          // padded LDS row stride (ints) for the epilogue bounce
__global__ __launch_bounds__(256, 3) void k1_gemm(const float* __restrict__ inp,
                                                  char* __restrict__ ws,
                                                  int* __restrict__ accOut) {
    __shared__ alignas(16) char smem[32800];
    char* As0 = smem;                  // 2 x 8192
    char* Bs0 = smem + 16384;          // 2 x 8192
    float* rmn = (float*)(smem + 32768);
    float* rmx = rmn + 4;
    int tid = threadIdx.x, lane = tid & 63, wave = tid >> 6;
    int wrow = lane & 15, g = lane >> 4;
    int bid = blockIdx.x;
    int xcd = bid & 7, slot = bid >> 3;           // 1536 blocks: 8 XCDs x 192 slots
    int mtile = xcd * 32 + slot / 6;
    int ntile = slot % 6;
    int t0 = mtile * BM, o0 = ntile * BN;
    const char* a8 = (const char*)(ws + WX_OFF);
    const char* w8 = (const char*)(ws + WINT_OFF);

    const char* asrc[2]; const char* bsrc[2];
    int ldso[2];
    #pragma unroll
    for (int i = 0; i < 2; ++i) {
        int c = i * 256 + tid, r = c >> 2, s = c & 3;
        asrc[i] = a8 + (size_t)(t0 + r) * HDIM + (s ^ swz4(r)) * 16;
        bsrc[i] = w8 + (size_t)(o0 + r) * HDIM + (s ^ swz4(r)) * 16;
        ldso[i] = (i * 256 + wave * 64) * 16;
    }

    int wm = wave & 1, wn = wave >> 1;            // wave tile: 64(t) x 64(o)
    int aofs[4], bofs[4];
    #pragma unroll
    for (int mi = 0; mi < 4; ++mi) { int r = wm * 64 + mi * 16 + wrow; aofs[mi] = r * BK + ((g ^ swz4(r)) * 16); }
    #pragma unroll
    for (int nf = 0; nf < 4; ++nf) { int r = wn * 64 + nf * 16 + wrow; bofs[nf] = r * BK + ((g ^ swz4(r)) * 16); }

    #pragma unroll
    for (int i = 0; i < 2; ++i) GLDS16(asrc[i], As0 + ldso[i]);
    #pragma unroll
    for (int i = 0; i < 2; ++i) GLDS16(bsrc[i], Bs0 + ldso[i]);
    #pragma unroll
    for (int i = 0; i < 2; ++i) GLDS16(asrc[i] + BK, As0 + 8192 + ldso[i]);
    #pragma unroll
    for (int i = 0; i < 2; ++i) GLDS16(bsrc[i] + BK, Bs0 + 8192 + ldso[i]);
    asm volatile("s_waitcnt vmcnt(4)" ::: "memory");
    __builtin_amdgcn_s_barrier();

    v4i acc[4][4] = {};
    for (int kt = 0; kt < NKT; ++kt) {
        int cur = kt & 1;
        const char* Ac = As0 + cur * 8192;
        const char* Bc = Bs0 + cur * 8192;
        u64x2 af[4], bf[4];
        #pragma unroll
        for (int mi = 0; mi < 4; ++mi) af[mi] = *(const u64x2*)(Ac + aofs[mi]);
        #pragma unroll
        for (int nf = 0; nf < 4; ++nf) bf[nf] = *(const u64x2*)(Bc + bofs[nf]);
        asm volatile("s_waitcnt lgkmcnt(0)" ::: "memory");
        __builtin_amdgcn_s_barrier();
        if (kt + 2 < NKT) {
            #pragma unroll
            for (int i = 0; i < 2; ++i) GLDS16(asrc[i] + (kt + 2) * BK, As0 + cur * 8192 + ldso[i]);
            #pragma unroll
            for (int i = 0; i < 2; ++i) GLDS16(bsrc[i] + (kt + 2) * BK, Bs0 + cur * 8192 + ldso[i]);
        }
        __builtin_amdgcn_s_setprio(1);
        #pragma unroll
        for (int mi = 0; mi < 4; ++mi)
            #pragma unroll
            for (int nf = 0; nf < 4; ++nf) {
                acc[mi][nf] = __builtin_amdgcn_mfma_i32_16x16x32_i8((long)af[mi][0], (long)bf[nf][0], acc[mi][nf], 0, 0, 0);
                acc[mi][nf] = __builtin_amdgcn_mfma_i32_16x16x32_i8((long)af[mi][1], (long)bf[nf][1], acc[mi][nf], 0, 0, 0);
            }
        __builtin_amdgcn_s_setprio(0);
        if (kt + 2 < NKT) {
            asm volatile("s_waitcnt vmcnt(4)" ::: "memory");
            __builtin_amdgcn_s_barrier();
        } else if (kt + 2 == NKT) {
            asm volatile("s_waitcnt vmcnt(0)" ::: "memory");
            __builtin_amdgcn_s_barrier();
        }
    }

    // ---- epilogue: LDS-bounce per mi-slice, vectorized 16B global I/O ----
    const float* bscale = (const float*)(ws + BS_OFF);
    const int* bint = (const int*)(ws + BINT_OFF);
    int* sAcc = (int*)smem;
    float lmn = 3.402823466e38f, lmx = -3.402823466e38f;
    #pragma unroll
    for (int mi = 0; mi < 4; ++mi) {
        __syncthreads();
        #pragma unroll
        for (int nf = 0; nf < 4; ++nf)
            #pragma unroll
            for (int r = 0; r < 4; ++r)
                sAcc[(wm * 16 + g * 4 + r) * SROW + wn * 64 + nf * 16 + wrow] = acc[mi][nf][r];
        __syncthreads();
        #pragma unroll
        for (int k = 0; k < 4; ++k) {
            int i4 = tid + k * 256;                // 1024 int4 = 32 rows x 32 int4
            int sr = i4 >> 5, c4 = i4 & 31;
            int t = t0 + (sr >> 4) * 64 + mi * 16 + (sr & 15);
            int col = o0 + c4 * 4;
            int4 a4 = *(const int4*)&sAcc[sr * SROW + c4 * 4];
            int4 b4 = *(const int4*)&bint[col];
            float4 bs4 = *(const float4*)&bscale[col];
            a4.x += b4.x; a4.y += b4.y; a4.z += b4.z; a4.w += b4.w;
            size_t idx = (size_t)t * HDIM + col;
            *(int4*)&accOut[idx] = a4;
            float4 x4 = *(const float4*)&inp[idx];
            float xa;
            xa = (float)a4.x * bs4.x + x4.x; lmn = fminf(lmn, xa); lmx = fmaxf(lmx, xa);
            xa = (float)a4.y * bs4.y + x4.y; lmn = fminf(lmn, xa); lmx = fmaxf(lmx, xa);
            xa = (float)a4.z * bs4.z + x4.z; lmn = fminf(lmn, xa); lmx = fmaxf(lmx, xa);
            xa = (float)a4.w * bs4.w + x4.w; lmn = fminf(lmn, xa); lmx = fmaxf(lmx, xa);
        }
    }
    #pragma unroll
    for (int off = 32; off; off >>= 1) {
        lmn = fminf(lmn, __shfl_down(lmn, off));
        lmx = fmaxf(lmx, __shfl_down(lmx, off));
    }
    __syncthreads();
    if (lane == 0) { rmn[wave] = lmn; rmx[wave] = lmx; }
    __syncthreads();
    if (tid == 0) {
        float mn = fminf(fminf(rmn[0], rmn[1]), fminf(rmn[2], rmn[3]));
        float mx = fmaxf(fmaxf(rmx[0], rmx[1]), fmaxf(rmx[2], rmx[3]));
        volatile unsigned* sc = (volatile unsigned*)(ws + SC_OFF);
        unsigned emn = fenc(mn), emx = fenc(mx);
        if (emn < sc[0]) atomicMin((unsigned*)&sc[0], emn);
        if (emx > sc[1]) atomicMax((unsigned*)&sc[1], emx);
    }
}

// ============ K2: finalize ln_in_scale s + frexp tables ============
__global__ __launch_bounds__(256) void k2_scale1(const float* __restrict__ pisf, char* __restrict__ ws) {
    __shared__ float s_sh;
    unsigned* sc = (unsigned*)(ws + SC_OFF);
    if (threadIdx.x == 0) {
        float mn = fdec(sc[0]), mx = fdec(sc[1]);
        float s = fmaxf(fmaxf(fabsf(mn), fabsf(mx)), 1e-8f) / 2097151.0f;  // n = 2^21-1
        ((float*)sc)[5] = s;
        s_sh = s;
        double r = (double)(*pisf) / (double)s;
        int ex; double mant = frexp(r, &ex);
        double m1 = floor(mant * 2147483648.0 + 0.5);
        ((double*)(ws + RSM1_OFF))[0] = m1 * exp2((double)(ex - 31));
    }
    __syncthreads();
    float s = s_sh;
    const float* bs = (const float*)(ws + BS_OFF);
    double* rs1 = (double*)(ws + RS1_OFF);
    for (int o = threadIdx.x; o < HDIM; o += 256) {
        double r = (double)bs[o] / (double)s;
        int ex; double mant = frexp(r, &ex);
        double m = floor(mant * 2147483648.0 + 0.5);
        rs1[o] = m * exp2((double)(ex - 31));
    }
}

// ============ K3F: fused requant + LN stats, 4-candidate window ============
// Round-10 lesson: both k3f variants sat at >64 VGPR -> 4 waves/SIMD (occupancy
// 20-27%) vs old k3's <=64 -> 8 waves (occ 33-43%); candidate count was
// irrelevant (12-cand == 4-cand == 116us). This version targets <=64 VGPR:
// channel tables live in LDS ([k][lane] layout: b32 conflict-free, b64 ~free),
// no next-row prefetch (8-wave TLP covers), no z[] (inline shifts).
__global__ __launch_bounds__(256) void k3f(char* __restrict__ ws, int* __restrict__ buf,
                                           const float* __restrict__ inp,
                                           const float* __restrict__ pisf) {
    int tid = threadIdx.x, lane = tid & 63, wave = tid >> 6;
    int wid = blockIdx.x * 4 + wave;
    __shared__ double rs1_l[768];
    __shared__ int    lnbi_l[768];
    __shared__ float  sfo_l[768];
    __shared__ float  smn[4][16], smx[4][16];
    {
        const double* rs1 = (const double*)(ws + RS1_OFF);
        const int* lnbi = (const int*)(ws + LNBI_OFF);
        const float* sfo = (const float*)(ws + SFO_OFF);
        for (int i = tid; i < HDIM; i += 256) {
            int kk = i >> 6;
            int ch = (i & 63) * 4 + (kk >> 2) * 256 + (kk & 3);   // channel of (lane=i&63, k=kk)
            rs1_l[i] = rs1[ch];
            lnbi_l[i] = lnbi[ch];
            sfo_l[i] = sfo[ch];
        }
    }
    if (lane < 16) { smn[wave][lane] = 3.402823466e38f; smx[wave][lane] = -3.402823466e38f; }
    __syncthreads();
    double rsm1 = *(const double*)(ws + RSM1_OFF);
    float inv_isf = 1.0f / *pisf;
    unsigned* fct = (unsigned*)(ws + FCT_OFF);
    int locMax = 0, locMin = 127;
    for (int rr = 0; rr < 4; ++rr) {
        size_t base = (size_t)(wid * 4 + rr) * HDIM;
        int4 a[3]; float4 x[3];
        #pragma unroll
        for (int c = 0; c < 3; ++c) {
            a[c] = ((const int4*)(buf + base))[lane + 64 * c];
            x[c] = ((const float4*)(inp + base))[lane + 64 * c];
        }
        int q[12];
        int sum = 0;
        #pragma unroll
        for (int c = 0; c < 3; ++c) {
            int av[4] = {a[c].x, a[c].y, a[c].z, a[c].w};
            float xv[4] = {x[c].x, x[c].y, x[c].z, x[c].w};
            #pragma unroll
            for (int j = 0; j < 4; ++j) {
                double q1 = rint((double)av[j] * rs1_l[(c * 4 + j) * 64 + lane]);
                int wxj = (int)rintf(xv[j] * inv_isf);
                double qq = q1 + rint((double)wxj * rsm1);
                qq = fmin(fmax(qq, -2097152.0), 2097151.0);   // clip [-2^21, 2^21-1]
                q[c * 4 + j] = (int)qq;
                sum += q[c * 4 + j];
            }
        }
        #pragma unroll
        for (int off = 32; off; off >>= 1) sum += __shfl_xor(sum, off);
        int mean = (int)rint((double)sum / 768.0);
        long long v0 = 0;
        #pragma unroll
        for (int k = 0; k < 12; ++k) { q[k] -= mean; v0 += (long long)q[k] * (long long)q[k]; }
        #pragma unroll
        for (int off = 32; off; off >>= 1) v0 += __shfl_xor(v0, off);
        #pragma unroll
        for (int c = 0; c < 3; ++c) {
            int4 y = {q[c * 4 + 0], q[c * 4 + 1], q[c * 4 + 2], q[c * 4 + 3]};
            ((int4*)(buf + base))[lane + 64 * c] = y;
        }
        double vd = (double)(v0 < 1 ? 1LL : v0);
        int sr = (int)ceil(0.5 * log2(vd) - 16.0);        // per-row shift, provably <= 11
        if (sr < 0) sr = 0;
        if (sr > 11) sr = 11;
        locMax = max(locMax, sr);
        locMin = min(locMin, sr);
        // hoist lnbi/sfo for this lane into regs (a/x dead now; regs reused)
        int tl[12]; float tf[12];
        #pragma unroll
        for (int k = 0; k < 12; ++k) { tl[k] = lnbi_l[k * 64 + lane]; tf[k] = sfo_l[k * 64 + lane]; }
        #pragma unroll
        for (int d = 0; d < 4; ++d) {                     // candidates s = sr+d (static d)
            int s = sr + d;
            if (s < 12) {                                 // wave-uniform predicate
                long long vs;
                if (d == 0 && sr == 0) vs = v0;
                else {
                    vs = 0;
                    #pragma unroll
                    for (int k = 0; k < 12; ++k) { int zz = q[k] >> s; vs += (long long)zz * (long long)zz; }
                    #pragma unroll
                    for (int off = 32; off; off >>= 1) vs += __shfl_xor(vs, off);
                }
                double std_int = floor(sqrt((double)vs)) * (double)(1 << s);
                if (std_int < 1.0) std_int = 1.0;         // degenerate guard
                long long factor = (long long)floor(2147483648.0 / std_int);
                if (lane == 0) fct[(size_t)(wid * 4 + rr) * 16 + s] = (unsigned)factor;
                float hmn = 3.402823466e38f, hmx = -3.402823466e38f;
                #pragma unroll
                for (int k = 0; k < 12; ++k) {
                    long long t = ((long long)q[k] * factor) >> 1;   // floor(y*factor/2)
                    int v2 = (int)t + tl[k];
                    float h = (float)v2 * tf[k];
                    hmn = fminf(hmn, h);
                    hmx = fmaxf(hmx, h);
                }
                #pragma unroll
                for (int off = 32; off; off >>= 1) {
                    hmn = fminf(hmn, __shfl_xor(hmn, off));
                    hmx = fmaxf(hmx, __shfl_xor(hmx, off));
                }
                if (lane == 0) {                          // LDS commit: cheap, wave-local
                    smn[wave][s] = fminf(smn[wave][s], hmn);
                    smx[wave][s] = fmaxf(smx[wave][s], hmx);
                }
            }
        }
    }
    if (lane == 0) {
        int* sc = (int*)(ws + SC_OFF);
        if (locMax > 0 && locMax > *(volatile int*)(sc + 4)) atomicMax(sc + 4, locMax);
        if (locMin < *(volatile int*)(sc + 8)) atomicMin(sc + 8, locMin);
    }
    // ---- end-of-block commit: reduce LDS across waves, guarded global atomics ----
    __syncthreads();
    if (tid < 16) {
        float mn = fminf(fminf(smn[0][tid], smn[1][tid]), fminf(smn[2][tid], smn[3][tid]));
        float mx = fmaxf(fmaxf(smx[0][tid], smx[1][tid]), fmaxf(smx[2][tid], smx[3][tid]));
        if (mn < 3.3e38f) {
            volatile unsigned* cmi = (volatile unsigned*)(ws + CMIN_OFF);
            unsigned e = fenc(mn);
            if (e < cmi[tid]) atomicMin((unsigned*)&cmi[tid], e);
        }
        if (mx > -3.3e38f) {
            volatile unsigned* cma = (volatile unsigned*)(ws + CMAX_OFF);
            unsigned e = fenc(mx);
            if (e > cma[tid]) atomicMax((unsigned*)&cma[tid], e);
        }
    }
}

// ============ K5A: window-sufficiency flag ============
__global__ void k5a_flag(char* __restrict__ ws) {
    if (threadIdx.x == 0) {
        int S = ((const int*)(ws + SC_OFF))[4];
        int smin = ((const int*)(ws + SC_OFF))[8];
        ((int*)(ws + SC_OFF))[9] = (S - smin > 3) ? 1 : 0;
    }
}

// ============ K4FB: exact fallback -- full single-candidate pass at shift S ============
__global__ __launch_bounds__(256) void k4_fb(char* __restrict__ ws, const int* __restrict__ buf) {
    if (*((volatile int*)(ws + SC_OFF) + 9) == 0) return;   // common path: ~free
    int tid = threadIdx.x, lane = tid & 63, wave = tid >> 6;
    int wid = blockIdx.x * 4 + wave;
    int S = ((const int*)(ws + SC_OFF))[4];
    const int* lnbi = (const int*)(ws + LNBI_OFF);
    const float* sfo = (const float*)(ws + SFO_OFF);
    unsigned* fct = (unsigned*)(ws + FCT_OFF);
    volatile unsigned* cmi = (volatile unsigned*)(ws + CMIN_OFF);
    volatile unsigned* cma = (volatile unsigned*)(ws + CMAX_OFF);
    int t_lnbi[12]; float t_sfo[12];
    #pragma unroll
    for (int c = 0; c < 3; ++c) {
        int o0 = (lane + 64 * c) * 4;
        #pragma unroll
        for (int j = 0; j < 4; ++j) { t_lnbi[c * 4 + j] = lnbi[o0 + j]; t_sfo[c * 4 + j] = sfo[o0 + j]; }
    }
    for (int rr = 0; rr < 4; ++rr) {
        size_t base = (size_t)(wid * 4 + rr) * HDIM;
        int yv[12];
        #pragma unroll
        for (int c = 0; c < 3; ++c) {
            int4 y4 = ((const int4*)(buf + base))[lane + 64 * c];
            yv[c * 4 + 0] = y4.x; yv[c * 4 + 1] = y4.y; yv[c * 4 + 2] = y4.z; yv[c * 4 + 3] = y4.w;
        }
        long long vs = 0;
        #pragma unroll
        for (int k = 0; k < 12; ++k) { int zz = yv[k] >> S; vs += (long long)zz * (long long)zz; }
        #pragma unroll
        for (int off = 32; off; off >>= 1) vs += __shfl_xor(vs, off);
        double std_int = floor(sqrt((double)vs)) * (double)(1 << S);
        if (std_int < 1.0) std_int = 1.0;
        long long factor = (long long)floor(2147483648.0 / std_int);
        if (lane == 0) fct[(size_t)(wid * 4 + rr) * 16 + S] = (unsigned)factor;
        float hmn = 3.402823466e38f, hmx = -3.402823466e38f;
        #pragma unroll
        for (int k = 0; k < 12; ++k) {
            long long t = ((long long)yv[k] * factor) >> 1;
            int v2 = (int)t + t_lnbi[k];
            float h = (float)v2 * t_sfo[k];
            hmn = fminf(hmn, h);
            hmx = fmaxf(hmx, h);
        }
        #pragma unroll
        for (int off = 32; off; off >>= 1) {
            hmn = fminf(hmn, __shfl_xor(hmn, off));
            hmx = fmaxf(hmx, __shfl_xor(hmx, off));
        }
        if (lane == 0) {
            unsigned e = fenc(hmn);
            if (e < cmi[S]) atomicMin((unsigned*)&cmi[S], e);
            e = fenc(hmx);
            if (e > cma[S]) atomicMax((unsigned*)&cma[S], e);
        }
    }
}

// ============ K5: select candidate for global shift -> s2 + rs2 table ============
__global__ __launch_bounds__(256) void k5_scale2(char* __restrict__ ws) {
    __shared__ float s_sh;
    if (threadIdx.x == 0) {
        int shift = ((const int*)(ws + SC_OFF))[4];
        float mn = fdec(((const unsigned*)(ws + CMIN_OFF))[shift]);
        float mx = fdec(((const unsigned*)(ws + CMAX_OFF))[shift]);
        float s2 = fmaxf(fmaxf(fabsf(mn), fabsf(mx)), 1e-8f) / 127.0f;
        ((float*)(ws + SC_OFF))[6] = s2;
        s_sh = s2;
    }
    __syncthreads();
    float s2 = s_sh;
    const float* sfo = (const float*)(ws + SFO_OFF);
    double* rs2 = (double*)(ws + RS2_OFF);
    for (int o = threadIdx.x; o < HDIM; o += 256) {
        double r = (double)sfo[o] / (double)s2;
        int ex; double mant = frexp(r, &ex);
        double m = floor(mant * 2147483648.0 + 0.5);
        rs2[o] = m * exp2((double)(ex - 31));
    }
}

// ============ K6: LN normalize + 8-bit requant + output; rs2/lnbi from LDS ============
// Same <=64-VGPR transform: t_rs2 (24 VGPR of doubles) -> LDS [k][lane] layout.
__global__ __launch_bounds__(256) void k6_out(char* __restrict__ ws, float* __restrict__ out) {
    int tid = threadIdx.x, lane = tid & 63, wave = tid >> 6;
    int wid = blockIdx.x * 4 + wave;
    __shared__ double rs2_l[768];
    __shared__ int    lnbi_l[768];
    {
        const double* rs2 = (const double*)(ws + RS2_OFF);
        const int* lnbi = (const int*)(ws + LNBI_OFF);
        for (int i = tid; i < HDIM; i += 256) {
            int kk = i >> 6;
            int ch = (i & 63) * 4 + (kk >> 2) * 256 + (kk & 3);
            rs2_l[i] = rs2[ch];
            lnbi_l[i] = lnbi[ch];
        }
    }
    __syncthreads();
    const unsigned* fct = (const unsigned*)(ws + FCT_OFF);
    int shift = ((const int*)(ws + SC_OFF))[4];
    float s2 = ((const float*)(ws + SC_OFF))[6];
    int* buf = (int*)out;
    int4 yP[3];
    {
        size_t b0 = (size_t)(wid * 4) * HDIM;
        #pragma unroll
        for (int c = 0; c < 3; ++c) yP[c] = ((const int4*)(buf + b0))[lane + 64 * c];
    }
    for (int rr = 0; rr < 4; ++rr) {
        int4 yN[3];
        if (rr < 3) {
            size_t nb = (size_t)(wid * 4 + rr + 1) * HDIM;
            #pragma unroll
            for (int c = 0; c < 3; ++c) yN[c] = ((const int4*)(buf + nb))[lane + 64 * c];
        }
        size_t base = (size_t)(wid * 4 + rr) * HDIM;
        long long factor = (long long)fct[(size_t)(wid * 4 + rr) * 16 + shift];
        int yv[12];
        #pragma unroll
        for (int c = 0; c < 3; ++c) {
            yv[c * 4 + 0] = yP[c].x; yv[c * 4 + 1] = yP[c].y; yv[c * 4 + 2] = yP[c].z; yv[c * 4 + 3] = yP[c].w;
        }
        #pragma unroll
        for (int c = 0; c < 3; ++c) {
            float4 r;
            float* rp = &r.x;
            #pragma unroll
            for (int j = 0; j < 4; ++j) {
                int k = c * 4 + j;
                long long t = ((long long)yv[k] * factor) >> 1;   // identical to k3f/k4_fb
                int v2 = (int)t + lnbi_l[k * 64 + lane];
                double q = rint((double)v2 * rs2_l[k * 64 + lane]);
                q = fmin(fmax(q, -128.0), 127.0);
                rp[j] = (float)q * s2;
            }
            ((float4*)(out + base))[lane + 64 * c] = r;
        }
        #pragma unroll
        for (int c = 0; c < 3; ++c) yP[c] = yN[c];
    }
    if (wid == 0 && tid == 0) out[(size_t)NTOK * HDIM] = s2;
}

extern "C" void kernel_launch(void* const* d_in, const int* in_sizes, int n_in,
                              void* d_out, int out_size, void* d_ws, size_t ws_size,
                              hipStream_t stream) {
    const float* hs   = (const float*)d_in[0];
    const float* phsf = (const float*)d_in[1];
    const float* inp  = (const float*)d_in[2];
    const float* pisf = (const float*)d_in[3];
    const float* W    = (const float*)d_in[4];
    const float* bias = (const float*)d_in[5];
    const float* ln_w = (const float*)d_in[6];
    const float* ln_b = (const float*)d_in[7];
    char* ws = (char*)d_ws;
    float* out = (float*)d_out;
    int* buf = (int*)d_out;   // d_out doubles as the 100MB int32 intermediate buffer

    k0_prep<<<HDIM, 256, 0, stream>>>(W, bias, ln_w, ln_b, phsf, ws);
    kp_a8<<<NTOK * HDIM / 4096, 256, 0, stream>>>(hs, phsf, ws);
    k1_gemm<<<(NTOK / BM) * (HDIM / BN), 256, 0, stream>>>(inp, ws, buf);
    k2_scale1<<<1, 256, 0, stream>>>(pisf, ws);
    k3f<<<NTOK / 16, 256, 0, stream>>>(ws, buf, inp, pisf);
    k5a_flag<<<1, 64, 0, stream>>>(ws);
    k4_fb<<<NTOK / 16, 256, 0, stream>>>(ws, buf);
    k5_scale2<<<1, 256, 0, stream>>>(ws);
    k6_out<<<NTOK / 16, 256, 0, stream>>>(ws, out);
}